// Round 1
// baseline (209.952 us; speedup 1.0000x reference)
//
#include <hip/hip_runtime.h>

#define N_NODES 100000
#define N_EDGES 1250000
#define IN_CH 128
#define OUT_CH 64

#define NPB 128           // nodes per bin; bin = row >> 7
#define ACCS2 33          // u64 acc row stride (pad): 128*33*8 = 33792 B LDS
#define NBINS 782         // ceil(100000/128)
#define BINCAP_DEF 2048   // per-bin edge cap; mean 1598, sigma ~40 (+11 sigma)
#define NB1 256           // binning blocks
#define B1T 512
#define CH1 ((N_EDGES + NB1 - 1) / NB1)   // 4883 edges per bin block
#define MAXU ((CH1 + B1T - 1) / B1T)      // 10 edges cached per thread
#define CURS_STRIDE 16    // cursor padded to 64 B per bin
#define GEMM_BLOCKS ((N_NODES + 127) / 128)  // 782 gemm blocks @ 128 nodes

// fixed-point: q = rn(val * 2^13), biased by 2^23 per contribution (sign-safe,
// ulp(2^23)=1.0 so no low-bit loss; lo-half total: 45*(2^23+4e5) << 2^32)
#define QSCALE 8192.0f
#define QBIAS_F 8388608.0f
#define QBIAS_U 8388608u
#define INV_QSCALE 1.220703125e-4f   // 2^-13
#define SCALE_DEG 33554432.0f        // 2^25 fixed-point for degree accum
#define INV_SCALE_DEG 2.9802322387695312e-08f

typedef __attribute__((ext_vector_type(8))) short short8;
typedef __attribute__((ext_vector_type(4))) float f32x4;

// round-to-nearest-even f32 -> bf16
__device__ inline unsigned int f2bf(float f) {
    unsigned int u = __float_as_uint(f);
    unsigned int r = ((u >> 16) & 1u) + 0x7FFFu;
    return (u + r) >> 16;
}
__device__ inline float bf_lo(unsigned int p) { return __uint_as_float(p << 16); }
__device__ inline float bf_hi(unsigned int p) { return __uint_as_float(p & 0xFFFF0000u); }

// biased fixed-point quantize of one packed bf16x2, scaled by sc = QSCALE*dis_col
__device__ inline unsigned long long qpacks(unsigned int p, float sc) {
    unsigned int lo = (unsigned int)__float2int_rn(fmaf(bf_lo(p), sc, QBIAS_F));
    unsigned int hi = (unsigned int)__float2int_rn(fmaf(bf_hi(p), sc, QBIAS_F));
    return ((unsigned long long)hi << 32) | (unsigned long long)lo;
}

// ---------------------------------------------------------------------------
// Init: W[128,64] fp32 -> Wb bf16 in MFMA A-fragment layout; cursor bases;
// zero the fixed-point degree array. 98 blocks x 256 = 25088 threads.
// ---------------------------------------------------------------------------
__global__ __launch_bounds__(256) void init_kernel(const float* __restrict__ W,
                                                   unsigned int* __restrict__ Wb,
                                                   int* __restrict__ cursor,
                                                   int* __restrict__ deg,
                                                   int bincap) {
    int g = blockIdx.x * 256 + threadIdx.x;
    if (g < NBINS) cursor[g * CURS_STRIDE] = g * bincap;
    if (g < 25000) *(uint4*)(deg + g * 4) = make_uint4(0u, 0u, 0u, 0u);  // 100000 ints
    if (g < 1024) {
        int c = g >> 8;
        int t4 = (g >> 6) & 3;
        int l = g & 63;
        int q = l >> 4, r15 = l & 15;
        unsigned int o[4];
#pragma unroll
        for (int jj = 0; jj < 4; ++jj) {
            float f0 = W[(c * 32 + q * 8 + 2 * jj)     * OUT_CH + t4 * 16 + r15];
            float f1 = W[(c * 32 + q * 8 + 2 * jj + 1) * OUT_CH + t4 * 16 + r15];
            o[jj] = f2bf(f0) | (f2bf(f1) << 16);
        }
        *(uint4*)(Wb + (size_t)g * 4) = make_uint4(o[0], o[1], o[2], o[3]);
    }
}

// ---------------------------------------------------------------------------
// Fused heterogeneous dispatch:
//   blocks [0, NB1)            : edge binning (+ fused fixed-point deg atomics)
//   blocks [NB1, NB1+GEMM_BLKS): bf16-MFMA GEMM hs = bf16(x @ W), UNSCALED
// The two halves are data-independent (gemm no longer pre-scales by dis), so
// the atomic/latency-bound binning overlaps the HBM/MFMA-bound GEMM.
// Record (4 B): (rowlocal<<17) | col   (7 + 17 bits). Weight only feeds deg.
// ---------------------------------------------------------------------------
__global__ __launch_bounds__(512) void fused_kernel(const float* __restrict__ x,
                                                    const unsigned int* __restrict__ Wb,
                                                    const int* __restrict__ ei,
                                                    const float* __restrict__ ew,
                                                    int* __restrict__ cursor,
                                                    int* __restrict__ deg,
                                                    int* __restrict__ brec,
                                                    unsigned int* __restrict__ hs,
                                                    int bincap) {
    __shared__ int hist[NBINS];
    __shared__ int base[NBINS];
    __shared__ int rank[NBINS];
    const int tid = threadIdx.x;

    if (blockIdx.x < NB1) {
        // ----- binning half -----
        for (int i = tid; i < NBINS; i += B1T) { hist[i] = 0; rank[i] = 0; }
        __syncthreads();

        const int e0 = blockIdx.x * CH1;
        const int e1 = (e0 + CH1 < N_EDGES) ? e0 + CH1 : N_EDGES;

        int rowv[MAXU], colv[MAXU];
#pragma unroll
        for (int u = 0; u < MAXU; ++u) {
            int e = e0 + tid + u * B1T;
            bool ok = e < e1;
            rowv[u] = ok ? ei[e] : -1;
            colv[u] = ok ? ei[N_EDGES + e] : 0;
            if (ok) {
                float wgt = ew[e];
                atomicAdd(&hist[rowv[u] >> 7], 1);
                // deterministic fixed-point weighted in-degree (replaces bin2)
                atomicAdd(&deg[rowv[u]], __float2int_rn(wgt * SCALE_DEG));
            }
        }
        __syncthreads();

        for (int i = tid; i < NBINS; i += B1T)
            if (hist[i] > 0) base[i] = atomicAdd(&cursor[i * CURS_STRIDE], hist[i]);
        __syncthreads();

#pragma unroll
        for (int u = 0; u < MAXU; ++u) {
            if (rowv[u] >= 0) {
                int bb = rowv[u] >> 7;
                int rk = atomicAdd(&rank[bb], 1);
                int idx = base[bb] + rk;
                if (idx < (bb + 1) * bincap)      // memory-safety guard only
                    brec[idx] = ((rowv[u] & 127) << 17) | colv[u];
            }
        }
    } else {
        // ----- GEMM half: 128 nodes per block, 8 waves x 16 rows -----
        const int blk  = blockIdx.x - NB1;
        const int w    = tid >> 6;
        const int lane = tid & 63;
        const int q    = lane >> 4, r15 = lane & 15;
        const int node = blk * 128 + w * 16 + r15;
        const int nl   = (node < N_NODES) ? node : N_NODES - 1;   // clamp loads
        const float* xrow = x + (size_t)nl * IN_CH;

        f32x4 acc[4];
#pragma unroll
        for (int t = 0; t < 4; ++t) acc[t] = (f32x4){0.f, 0.f, 0.f, 0.f};

#pragma unroll
        for (int c = 0; c < 4; ++c) {
            float4 xa = *(const float4*)(xrow + c * 32 + q * 8);
            float4 xb = *(const float4*)(xrow + c * 32 + q * 8 + 4);
            short8 bfrag;
            bfrag[0] = (short)f2bf(xa.x); bfrag[1] = (short)f2bf(xa.y);
            bfrag[2] = (short)f2bf(xa.z); bfrag[3] = (short)f2bf(xa.w);
            bfrag[4] = (short)f2bf(xb.x); bfrag[5] = (short)f2bf(xb.y);
            bfrag[6] = (short)f2bf(xb.z); bfrag[7] = (short)f2bf(xb.w);
#pragma unroll
            for (int t = 0; t < 4; ++t) {
                short8 afrag = *(const short8*)(Wb + (size_t)((c * 4 + t) * 64 + lane) * 4);
                acc[t] = __builtin_amdgcn_mfma_f32_16x16x32_bf16(afrag, bfrag, acc[t], 0, 0, 0);
            }
        }

        if (node < N_NODES) {
#pragma unroll
            for (int t = 0; t < 4; ++t) {
                unsigned int p0 = f2bf(acc[t][0]) | (f2bf(acc[t][1]) << 16);
                unsigned int p1 = f2bf(acc[t][2]) | (f2bf(acc[t][3]) << 16);
                *(uint2*)(hs + (size_t)node * 32 + t * 8 + q * 2) = make_uint2(p0, p1);
            }
        }
    }
}

// ---------------------------------------------------------------------------
// Bin-gather: one 512-thread block per 128-node bin. u64-packed LDS atomics
// (2 biased fixed-point channels per ds_add_u64). Col-side dis = rsqrt(deg)
// reconstructed per edge from the L2-resident deg array (8-lane broadcast
// load + cheap VALU); row-side dis applied at writeout. No dis array.
// ---------------------------------------------------------------------------
__global__ __launch_bounds__(512) void gather_kernel(const int* __restrict__ cursor,
                                                     const int* __restrict__ brec,
                                                     const uint4* __restrict__ hs, // 8/row
                                                     const int* __restrict__ deg,
                                                     const float* __restrict__ b,
                                                     float* __restrict__ out,
                                                     int bincap) {
    __shared__ unsigned long long acc[NPB * ACCS2];   // 33792 B
    __shared__ int cnt[NPB];
    const int tid = threadIdx.x;
    const int blk = blockIdx.x;
    for (int k = tid; k < NPB * ACCS2; k += 512) acc[k] = 0ull;
    if (tid < NPB) cnt[tid] = 0;
    __syncthreads();

    const int rbase = blk * bincap;
    int m = cursor[blk * CURS_STRIDE] - rbase;
    if (m > bincap) m = bincap;

    const int wid = tid >> 6, lane = tid & 63;
    const int sub = lane >> 3, l8 = lane & 7;

    for (int j0 = wid * 16; j0 < m; j0 += 128) {
        int jA = j0 + sub;
        int jB = j0 + 8 + sub;
        bool okA = jA < m, okB = jB < m;
        int recA = okA ? brec[rbase + jA] : 0;
        int recB = okB ? brec[rbase + jB] : 0;
        uint4 pA = make_uint4(0, 0, 0, 0), pB = make_uint4(0, 0, 0, 0);
        if (okA) pA = hs[(size_t)(recA & 0x1FFFF) * 8 + l8];
        if (okB) pB = hs[(size_t)(recB & 0x1FFFF) * 8 + l8];
        if (okA) {
            float d  = (float)deg[recA & 0x1FFFF] * INV_SCALE_DEG;
            float sc = (d == 0.0f) ? 0.0f : QSCALE * rsqrtf(d);
            int ba = (recA >> 17) * ACCS2 + 4 * l8;
            atomicAdd(&acc[ba + 0], qpacks(pA.x, sc));
            atomicAdd(&acc[ba + 1], qpacks(pA.y, sc));
            atomicAdd(&acc[ba + 2], qpacks(pA.z, sc));
            atomicAdd(&acc[ba + 3], qpacks(pA.w, sc));
            if (l8 == 0) atomicAdd(&cnt[recA >> 17], 1);
        }
        if (okB) {
            float d  = (float)deg[recB & 0x1FFFF] * INV_SCALE_DEG;
            float sc = (d == 0.0f) ? 0.0f : QSCALE * rsqrtf(d);
            int bb = (recB >> 17) * ACCS2 + 4 * l8;
            atomicAdd(&acc[bb + 0], qpacks(pB.x, sc));
            atomicAdd(&acc[bb + 1], qpacks(pB.y, sc));
            atomicAdd(&acc[bb + 2], qpacks(pB.z, sc));
            atomicAdd(&acc[bb + 3], qpacks(pB.w, sc));
            if (l8 == 0) atomicAdd(&cnt[recB >> 17], 1);
        }
    }
    __syncthreads();

    // writeout: wave w handles node-locals [w*16, w*16+16); lane = channel c.
    // channel c lives in 32-bit half (c&1) of u64 slot (c>>1).
    const unsigned int* acc32 = (const unsigned int*)acc;
    float bc = b[lane];
    int half = lane & 1, slot = lane >> 1;
#pragma unroll 4
    for (int r = 0; r < 16; ++r) {
        int nl = wid * 16 + r;
        int node = blk * NPB + nl;
        if (node < N_NODES) {
            unsigned int raw = acc32[(nl * ACCS2 + slot) * 2 + half];
            int qsum = (int)(raw - (unsigned int)cnt[nl] * QBIAS_U);
            float dr = (float)deg[node] * INV_SCALE_DEG;
            float di = (dr == 0.0f) ? 0.0f : (1.0f / sqrtf(dr));
            out[(size_t)node * OUT_CH + lane] = (float)qsum * (di * INV_QSCALE) + bc;
        }
    }
}

extern "C" void kernel_launch(void* const* d_in, const int* in_sizes, int n_in,
                              void* d_out, int out_size, void* d_ws, size_t ws_size,
                              hipStream_t stream) {
    const float* x  = (const float*)d_in[0];
    const int*   ei = (const int*)d_in[1];
    const float* ew = (const float*)d_in[2];
    const float* W  = (const float*)d_in[3];
    const float* b  = (const float*)d_in[4];
    float* out = (float*)d_out;

    // Workspace layout (4-byte units)
    unsigned int* hs = (unsigned int*)d_ws;                   // N*32 uints (12.8 MB)
    unsigned int* Wb = hs + (size_t)N_NODES * 32;             // 4096 uints
    int* cursor = (int*)(Wb + 4096);                          // NBINS*16 (padded)
    int* deg    = cursor + NBINS * CURS_STRIDE;               // N ints (fixed-point)
    int* brec   = deg + N_NODES;                              // NBINS*bincap ints (4 B recs)
    size_t used = (size_t)N_NODES * 32 + 4096 + (size_t)NBINS * CURS_STRIDE
                + (size_t)N_NODES;
    size_t rem  = (ws_size / 4 > used) ? ws_size / 4 - used : 0;
    int bincap  = (int)(rem / (size_t)NBINS);   // brec = 1 unit per slot now
    if (bincap > BINCAP_DEF) bincap = BINCAP_DEF;

    init_kernel<<<98, 256, 0, stream>>>(W, Wb, cursor, deg, bincap);
    fused_kernel<<<NB1 + GEMM_BLOCKS, 512, 0, stream>>>(x, Wb, ei, ew, cursor, deg,
                                                        brec, hs, bincap);
    gather_kernel<<<NBINS, 512, 0, stream>>>(cursor, brec, (const uint4*)hs,
                                             deg, b, out, bincap);
}

// Round 2
// 164.904 us; speedup vs baseline: 1.2732x; 1.2732x over previous
//
#include <hip/hip_runtime.h>

#define N_NODES 100000
#define N_EDGES 1250000
#define IN_CH 128
#define OUT_CH 64

#define NPB 128           // nodes per bin; bin = row >> 7
#define ACCS2 33          // u64 acc row stride (pad): 128*33*8 = 33792 B LDS
#define NBINS 782         // ceil(100000/128)
#define BINCAP_DEF 2048   // per-bin edge cap; mean 1598, sigma ~40 (+11 sigma)
#define NB1 256           // binning blocks
#define B1T 512
#define CH1 ((N_EDGES + NB1 - 1) / NB1)   // 4883 edges per bin block
#define MAXU ((CH1 + B1T - 1) / B1T)      // 10 edges cached per thread
#define CURS_STRIDE 16    // cursor padded to 64 B per bin
#define GEMM_BLOCKS ((N_NODES + 127) / 128)  // 782 gemm blocks @ 128 nodes

// fixed-point: q = rn(val * sc), biased by 2^23 per contribution (sign-safe,
// ulp(2^23)=1.0; lo-half total stays << 2^32 at max ~45 edges/row)
#define QSCALE 8192.0f
#define QBIAS_F 8388608.0f
#define QBIAS_U 8388608u
#define INV_QSCALE 1.220703125e-4f   // 2^-13
#define SCALE_DEG 33554432.0f        // 2^25 fixed-point for degree accum
#define INV_SCALE_DEG 2.9802322387695312e-08f

typedef __attribute__((ext_vector_type(8))) short short8;
typedef __attribute__((ext_vector_type(4))) float f32x4;

// round-to-nearest-even f32 -> bf16
__device__ inline unsigned int f2bf(float f) {
    unsigned int u = __float_as_uint(f);
    unsigned int r = ((u >> 16) & 1u) + 0x7FFFu;
    return (u + r) >> 16;
}
__device__ inline float bf_lo(unsigned int p) { return __uint_as_float(p << 16); }
__device__ inline float bf_hi(unsigned int p) { return __uint_as_float(p & 0xFFFF0000u); }

// biased fixed-point quantize of one packed bf16x2, scaled by sc = QSCALE*dis_col
__device__ inline unsigned long long qpacks(unsigned int p, float sc) {
    unsigned int lo = (unsigned int)__float2int_rn(fmaf(bf_lo(p), sc, QBIAS_F));
    unsigned int hi = (unsigned int)__float2int_rn(fmaf(bf_hi(p), sc, QBIAS_F));
    return ((unsigned long long)hi << 32) | (unsigned long long)lo;
}

// ---------------------------------------------------------------------------
// Init: W[128,64] fp32 -> Wb bf16 in MFMA A-fragment layout; cursor bases.
// 4 blocks x 256 = 1024 threads.
// ---------------------------------------------------------------------------
__global__ __launch_bounds__(256) void init_kernel(const float* __restrict__ W,
                                                   unsigned int* __restrict__ Wb,
                                                   int* __restrict__ cursor,
                                                   int bincap) {
    int g = blockIdx.x * 256 + threadIdx.x;   // 1024 lane-slots
    if (g < NBINS) cursor[g * CURS_STRIDE] = g * bincap;

    int c = g >> 8;
    int t4 = (g >> 6) & 3;
    int l = g & 63;
    int q = l >> 4, r15 = l & 15;
    unsigned int o[4];
#pragma unroll
    for (int jj = 0; jj < 4; ++jj) {
        float f0 = W[(c * 32 + q * 8 + 2 * jj)     * OUT_CH + t4 * 16 + r15];
        float f1 = W[(c * 32 + q * 8 + 2 * jj + 1) * OUT_CH + t4 * 16 + r15];
        o[jj] = f2bf(f0) | (f2bf(f1) << 16);
    }
    *(uint4*)(Wb + (size_t)g * 4) = make_uint4(o[0], o[1], o[2], o[3]);
}

// ---------------------------------------------------------------------------
// Fused heterogeneous dispatch:
//   blocks [0, NB1)            : edge binning (8 B records, weight included)
//   blocks [NB1, NB1+GEMM_BLKS): bf16-MFMA GEMM hs = bf16(x @ W), UNSCALED
// Data-independent halves: atomic/latency-bound binning overlaps the
// HBM/MFMA-bound GEMM. NO global atomics here (round-1 post-mortem: 1.25M
// device-scope scattered atomicAdds cost 82 us + 50 MB of RMW write traffic).
// Record: x = (rowlocal<<17)|col  (7+17 bits), y = weight bits.
// ---------------------------------------------------------------------------
__global__ __launch_bounds__(512) void fused_kernel(const float* __restrict__ x,
                                                    const unsigned int* __restrict__ Wb,
                                                    const int* __restrict__ ei,
                                                    const float* __restrict__ ew,
                                                    int* __restrict__ cursor,
                                                    int2* __restrict__ brec,
                                                    unsigned int* __restrict__ hs,
                                                    int bincap) {
    __shared__ int hist[NBINS];
    __shared__ int base[NBINS];
    __shared__ int rank[NBINS];
    const int tid = threadIdx.x;

    if (blockIdx.x < NB1) {
        // ----- binning half -----
        for (int i = tid; i < NBINS; i += B1T) { hist[i] = 0; rank[i] = 0; }
        __syncthreads();

        const int e0 = blockIdx.x * CH1;
        const int e1 = (e0 + CH1 < N_EDGES) ? e0 + CH1 : N_EDGES;

        int rowv[MAXU], colv[MAXU];
        float wv[MAXU];
#pragma unroll
        for (int u = 0; u < MAXU; ++u) {
            int e = e0 + tid + u * B1T;
            bool ok = e < e1;
            rowv[u] = ok ? ei[e] : -1;
            colv[u] = ok ? ei[N_EDGES + e] : 0;
            wv[u]   = ok ? ew[e] : 0.0f;
            if (ok) atomicAdd(&hist[rowv[u] >> 7], 1);
        }
        __syncthreads();

        for (int i = tid; i < NBINS; i += B1T)
            if (hist[i] > 0) base[i] = atomicAdd(&cursor[i * CURS_STRIDE], hist[i]);
        __syncthreads();

#pragma unroll
        for (int u = 0; u < MAXU; ++u) {
            if (rowv[u] >= 0) {
                int bb = rowv[u] >> 7;
                int rk = atomicAdd(&rank[bb], 1);
                int idx = base[bb] + rk;
                if (idx < (bb + 1) * bincap)      // memory-safety guard only
                    brec[idx] = make_int2(((rowv[u] & 127) << 17) | colv[u],
                                          __float_as_int(wv[u]));
            }
        }
    } else {
        // ----- GEMM half: 128 nodes per block, 8 waves x 16 rows -----
        const int blk  = blockIdx.x - NB1;
        const int w    = tid >> 6;
        const int lane = tid & 63;
        const int q    = lane >> 4, r15 = lane & 15;
        const int node = blk * 128 + w * 16 + r15;
        const int nl   = (node < N_NODES) ? node : N_NODES - 1;   // clamp loads
        const float* xrow = x + (size_t)nl * IN_CH;

        f32x4 acc[4];
#pragma unroll
        for (int t = 0; t < 4; ++t) acc[t] = (f32x4){0.f, 0.f, 0.f, 0.f};

#pragma unroll
        for (int c = 0; c < 4; ++c) {
            float4 xa = *(const float4*)(xrow + c * 32 + q * 8);
            float4 xb = *(const float4*)(xrow + c * 32 + q * 8 + 4);
            short8 bfrag;
            bfrag[0] = (short)f2bf(xa.x); bfrag[1] = (short)f2bf(xa.y);
            bfrag[2] = (short)f2bf(xa.z); bfrag[3] = (short)f2bf(xa.w);
            bfrag[4] = (short)f2bf(xb.x); bfrag[5] = (short)f2bf(xb.y);
            bfrag[6] = (short)f2bf(xb.z); bfrag[7] = (short)f2bf(xb.w);
#pragma unroll
            for (int t = 0; t < 4; ++t) {
                short8 afrag = *(const short8*)(Wb + (size_t)((c * 4 + t) * 64 + lane) * 4);
                acc[t] = __builtin_amdgcn_mfma_f32_16x16x32_bf16(afrag, bfrag, acc[t], 0, 0, 0);
            }
        }

        if (node < N_NODES) {
#pragma unroll
            for (int t = 0; t < 4; ++t) {
                unsigned int p0 = f2bf(acc[t][0]) | (f2bf(acc[t][1]) << 16);
                unsigned int p1 = f2bf(acc[t][2]) | (f2bf(acc[t][3]) << 16);
                *(uint2*)(hs + (size_t)node * 32 + t * 8 + q * 2) = make_uint2(p0, p1);
            }
        }
    }
}

// ---------------------------------------------------------------------------
// Degree pass: one block per bin. INT fixed-point LDS deg accumulate -> dis.
// Deterministic; ~7 us total (brec re-read is L2-resident).
// ---------------------------------------------------------------------------
__global__ __launch_bounds__(256) void bin2_kernel(const int* __restrict__ cursor,
                                                   const int2* __restrict__ brec,
                                                   float* __restrict__ dis_g,
                                                   int bincap) {
    __shared__ int deg[NPB];
    const int t = threadIdx.x;
    const int b = blockIdx.x;
    if (t < NPB) deg[t] = 0;
    __syncthreads();

    const int rbase = b * bincap;
    int m = cursor[b * CURS_STRIDE] - rbase;
    if (m > bincap) m = bincap;

    for (int j = t; j < m; j += 256) {
        int2 rec = brec[rbase + j];
        atomicAdd(&deg[rec.x >> 17], __float2int_rn(__int_as_float(rec.y) * SCALE_DEG));
    }
    __syncthreads();

    int node = b * NPB + t;
    if (t < NPB && node < N_NODES) {
        float d = (float)deg[t] * INV_SCALE_DEG;
        dis_g[node] = (d == 0.0f) ? 0.0f : (1.0f / sqrtf(d));
    }
}

// ---------------------------------------------------------------------------
// Bin-gather: one 512-thread block per 128-node bin. u64-packed LDS atomics
// (2 biased fixed-point channels per ds_add_u64). Col-side scale = precomputed
// dis[col] (400 KB, L2-resident, broadcast across the 8-lane group); row-side
// dis applied at writeout.
// ---------------------------------------------------------------------------
__global__ __launch_bounds__(512) void gather_kernel(const int* __restrict__ cursor,
                                                     const int2* __restrict__ brec,
                                                     const uint4* __restrict__ hs, // 8/row
                                                     const float* __restrict__ dis,
                                                     const float* __restrict__ b,
                                                     float* __restrict__ out,
                                                     int bincap) {
    __shared__ unsigned long long acc[NPB * ACCS2];   // 33792 B
    __shared__ int cnt[NPB];
    const int tid = threadIdx.x;
    const int blk = blockIdx.x;
    for (int k = tid; k < NPB * ACCS2; k += 512) acc[k] = 0ull;
    if (tid < NPB) cnt[tid] = 0;
    __syncthreads();

    const int rbase = blk * bincap;
    int m = cursor[blk * CURS_STRIDE] - rbase;
    if (m > bincap) m = bincap;

    const int wid = tid >> 6, lane = tid & 63;
    const int sub = lane >> 3, l8 = lane & 7;

    for (int j0 = wid * 16; j0 < m; j0 += 128) {
        int jA = j0 + sub;
        int jB = j0 + 8 + sub;
        bool okA = jA < m, okB = jB < m;
        int recA = okA ? brec[rbase + jA].x : 0;
        int recB = okB ? brec[rbase + jB].x : 0;
        uint4 pA = make_uint4(0, 0, 0, 0), pB = make_uint4(0, 0, 0, 0);
        if (okA) pA = hs[(size_t)(recA & 0x1FFFF) * 8 + l8];
        if (okB) pB = hs[(size_t)(recB & 0x1FFFF) * 8 + l8];
        if (okA) {
            float sc = QSCALE * dis[recA & 0x1FFFF];
            int ba = (recA >> 17) * ACCS2 + 4 * l8;
            atomicAdd(&acc[ba + 0], qpacks(pA.x, sc));
            atomicAdd(&acc[ba + 1], qpacks(pA.y, sc));
            atomicAdd(&acc[ba + 2], qpacks(pA.z, sc));
            atomicAdd(&acc[ba + 3], qpacks(pA.w, sc));
            if (l8 == 0) atomicAdd(&cnt[recA >> 17], 1);
        }
        if (okB) {
            float sc = QSCALE * dis[recB & 0x1FFFF];
            int bb = (recB >> 17) * ACCS2 + 4 * l8;
            atomicAdd(&acc[bb + 0], qpacks(pB.x, sc));
            atomicAdd(&acc[bb + 1], qpacks(pB.y, sc));
            atomicAdd(&acc[bb + 2], qpacks(pB.z, sc));
            atomicAdd(&acc[bb + 3], qpacks(pB.w, sc));
            if (l8 == 0) atomicAdd(&cnt[recB >> 17], 1);
        }
    }
    __syncthreads();

    // writeout: wave w handles node-locals [w*16, w*16+16); lane = channel c.
    // channel c lives in 32-bit half (c&1) of u64 slot (c>>1).
    const unsigned int* acc32 = (const unsigned int*)acc;
    float bc = b[lane];
    int half = lane & 1, slot = lane >> 1;
#pragma unroll 4
    for (int r = 0; r < 16; ++r) {
        int nl = wid * 16 + r;
        int node = blk * NPB + nl;
        if (node < N_NODES) {
            unsigned int raw = acc32[(nl * ACCS2 + slot) * 2 + half];
            int qsum = (int)(raw - (unsigned int)cnt[nl] * QBIAS_U);
            float di = dis[node] * INV_QSCALE;
            out[(size_t)node * OUT_CH + lane] = (float)qsum * di + bc;
        }
    }
}

extern "C" void kernel_launch(void* const* d_in, const int* in_sizes, int n_in,
                              void* d_out, int out_size, void* d_ws, size_t ws_size,
                              hipStream_t stream) {
    const float* x  = (const float*)d_in[0];
    const int*   ei = (const int*)d_in[1];
    const float* ew = (const float*)d_in[2];
    const float* W  = (const float*)d_in[3];
    const float* b  = (const float*)d_in[4];
    float* out = (float*)d_out;

    // Workspace layout (4-byte units)
    unsigned int* hs = (unsigned int*)d_ws;                   // N*32 uints (12.8 MB)
    unsigned int* Wb = hs + (size_t)N_NODES * 32;             // 4096 uints
    int*   cursor  = (int*)(Wb + 4096);                       // NBINS*16 (padded)
    float* dis     = (float*)(cursor + NBINS * CURS_STRIDE);  // N
    int2*  brec    = (int2*)(dis + N_NODES);                  // NBINS*bincap int2
    size_t used = (size_t)N_NODES * 32 + 4096 + (size_t)NBINS * CURS_STRIDE
                + (size_t)N_NODES;
    size_t rem  = (ws_size / 4 > used) ? ws_size / 4 - used : 0;
    int bincap  = (int)(rem / (2 * (size_t)NBINS));   // brec = 2 units per slot
    if (bincap > BINCAP_DEF) bincap = BINCAP_DEF;

    init_kernel<<<4, 256, 0, stream>>>(W, Wb, cursor, bincap);
    fused_kernel<<<NB1 + GEMM_BLOCKS, 512, 0, stream>>>(x, Wb, ei, ew, cursor,
                                                        brec, hs, bincap);
    bin2_kernel<<<NBINS, 256, 0, stream>>>(cursor, brec, dis, bincap);
    gather_kernel<<<NBINS, 512, 0, stream>>>(cursor, brec, (const uint4*)hs,
                                             dis, b, out, bincap);
}